// Round 7
// baseline (1661.131 us; speedup 1.0000x reference)
//
#include <hip/hip_runtime.h>
#include <hip/hip_bf16.h>
#include <math.h>

#define LRELU_SLOPE 0.2f
typedef __hip_bfloat16 bf16;
typedef __hip_bfloat162 bf16x2;

typedef short s8v __attribute__((ext_vector_type(8)));   // 8 bf16 (4 VGPRs)
typedef float f4v __attribute__((ext_vector_type(4)));   // MFMA acc

__device__ __forceinline__ float lrelu(float v) { return v > 0.f ? v : LRELU_SLOPE * v; }

__device__ __forceinline__ void st2(bf16* p, float x, float y) {
  float2 f{x, y};
  *(bf16x2*)p = __float22bfloat162_rn(f);
}
__device__ __forceinline__ void st2(float* p, float x, float y) {
  *(float2*)p = float2{x, y};
}

// nontemporal variants: bypass caches so the streaming output doesn't evict the h gather set
__device__ __forceinline__ void st2_nt(bf16* p, float x, float y) {
  float2 f{x, y};
  bf16x2 v = __float22bfloat162_rn(f);
  __builtin_nontemporal_store(*(unsigned int*)&v, (unsigned int*)p);
}
__device__ __forceinline__ void st2_nt(float* p, float x, float y) {
  __builtin_nontemporal_store(x, p);
  __builtin_nontemporal_store(y, p + 1);
}

// ---------------- zero helper (avoid hipMemsetAsync in capture) ----------------

__global__ void k_zero(unsigned int* __restrict__ p, long n) {
  long i = (long)blockIdx.x * blockDim.x + threadIdx.x;
  if (i < n) p[i] = 0u;
}

__global__ void k_zero_out(float* __restrict__ out, int n) {
  int i = blockIdx.x * blockDim.x + threadIdx.x;
  if (i < n) out[i] = 0.f;
}

// ---------------- dtype prep: x -> bf16, W -> bf16 transposed ----------------

__global__ void k_cvt(const float* __restrict__ x, bf16* __restrict__ xb, long n) {
  long i = (long)blockIdx.x * blockDim.x + threadIdx.x;
  if (i < n) xb[i] = __float2bfloat16(x[i]);
}

// W[K][NN] (f32) -> Wt[NN][K] (bf16)
__global__ void k_tw(const float* __restrict__ W, bf16* __restrict__ Wt, int K, int NN) {
  int i = blockIdx.x * blockDim.x + threadIdx.x;
  if (i >= K * NN) return;
  int k = i / NN, n = i - k * NN;
  Wt[(size_t)n * K + k] = __float2bfloat16(W[i]);
}

// ---------------- preprocessing: counting-sort edges by dst ----------------

__global__ void k_hist(const int* __restrict__ dst, int* __restrict__ deg, int E, int Et) {
  int e = blockIdx.x * blockDim.x + threadIdx.x;
  if (e >= Et) return;
  int d = (e < E) ? dst[e] : (e - E);   // self-loops appended
  atomicAdd(&deg[d], 1);
}

// also used for graph histogram over batch[]
__global__ void k_hist1(const int* __restrict__ idx, int* __restrict__ deg, int n) {
  int i = blockIdx.x * blockDim.x + threadIdx.x;
  if (i < n) atomicAdd(&deg[idx[i]], 1);
}

__global__ void k_scan1(const int* __restrict__ deg, int* __restrict__ offs,
                        int* __restrict__ bsum, int n) {
  __shared__ int sd[256];
  int t = threadIdx.x;
  int base = blockIdx.x * 1024 + t * 4;
  int v[4]; int tsum = 0;
#pragma unroll
  for (int i = 0; i < 4; ++i) { v[i] = (base + i < n) ? deg[base + i] : 0; tsum += v[i]; }
  sd[t] = tsum;
  __syncthreads();
  for (int off = 1; off < 256; off <<= 1) {
    int x = (t >= off) ? sd[t - off] : 0;
    __syncthreads();
    sd[t] += x;
    __syncthreads();
  }
  int excl = sd[t] - tsum;
#pragma unroll
  for (int i = 0; i < 4; ++i) { if (base + i < n) offs[base + i] = excl; excl += v[i]; }
  if (t == 255) bsum[blockIdx.x] = sd[255];
}

__global__ void k_scan2(int* bsum, int nb) {
  if (threadIdx.x == 0 && blockIdx.x == 0) {
    int run = 0;
    for (int i = 0; i < nb; ++i) { int t = bsum[i]; bsum[i] = run; run += t; }
  }
}

__global__ void k_scan3(int* __restrict__ offs, const int* __restrict__ bsum, int n, int total) {
  int t = threadIdx.x;
  int base = blockIdx.x * 1024 + t * 4;
  int add = bsum[blockIdx.x];
#pragma unroll
  for (int i = 0; i < 4; ++i) if (base + i < n) offs[base + i] += add;
  if (blockIdx.x == 0 && t == 0) offs[n] = total;
}

__global__ void k_scatter(const int* __restrict__ src, const int* __restrict__ dst,
                          const int* __restrict__ offs, int* __restrict__ cur,
                          int* __restrict__ ssrc, int E, int Et) {
  int e = blockIdx.x * blockDim.x + threadIdx.x;
  if (e >= Et) return;
  int s, d;
  if (e < E) { s = src[e]; d = dst[e]; } else { s = d = e - E; }
  int pos = offs[d] + atomicAdd(&cur[d], 1);
  ssrc[pos] = s;
}

// ---------------- bf16 MFMA GEMM: C[M,NN](bf16) = A[M,K](bf16) @ Wt[NN,K](bf16)^T ----

__global__ __launch_bounds__(256) void k_gemm_mfma(const bf16* __restrict__ A,
                                                   const bf16* __restrict__ Wt,
                                                   bf16* __restrict__ C,
                                                   int K, int NN) {
  __shared__ __align__(16) short sA[64 * 64];   // 8 KB, 64 rows x 64 cols bf16
  int t = threadIdx.x;
  int wv = t >> 6, lane = t & 63;
  int quad = lane >> 4, l15 = lane & 15;
  size_t bm0 = (size_t)blockIdx.x * 64;
  int bn0 = blockIdx.y * 64;
  const bf16* Ab = A + bm0 * K;
  const bf16* Bp = Wt + (size_t)(bn0 + wv * 16 + l15) * K;  // this lane's weight row
  f4v acc[4] = {f4v{0,0,0,0}, f4v{0,0,0,0}, f4v{0,0,0,0}, f4v{0,0,0,0}};

  for (int kb = 0; kb < K; kb += 64) {
#pragma unroll
    for (int j = 0; j < 2; ++j) {
      int idx = j * 256 + t;
      int row = idx >> 3, p = idx & 7;
      int c = p ^ (row & 7);                  // global 16B-chunk landing at pos p
      const bf16* g = Ab + (size_t)row * K + kb + c * 8;
      __builtin_amdgcn_global_load_lds(
          (const __attribute__((address_space(1))) void*)g,
          (__attribute__((address_space(3))) void*)((char*)sA + (size_t)(j * 256 + wv * 64) * 16),
          16, 0, 0);
    }
    __syncthreads();
#pragma unroll
    for (int kk = 0; kk < 2; ++kk) {
      s8v bfrag = *(const s8v*)(Bp + kb + kk * 32 + quad * 8);
#pragma unroll
      for (int ms = 0; ms < 4; ++ms) {
        int row = ms * 16 + l15;
        int pos = (kk * 4 + quad) ^ (row & 7);
        s8v afrag = *(const s8v*)((const char*)sA + (size_t)row * 128 + pos * 16);
        acc[ms] = __builtin_amdgcn_mfma_f32_16x16x32_bf16(afrag, bfrag, acc[ms], 0, 0, 0);
      }
    }
    __syncthreads();
  }
  // C/D layout: col = lane&15, row = quad*4 + reg  [m89/m91 verified]
  int coln = bn0 + wv * 16 + l15;
#pragma unroll
  for (int ms = 0; ms < 4; ++ms)
#pragma unroll
    for (int r = 0; r < 4; ++r)
      C[(bm0 + ms * 16 + quad * 4 + r) * NN + coln] = __float2bfloat16(acc[ms][r]);
}

// ---------------- attention logits al_s/al_d: one wave per node ----------------

__global__ void k_al(const bf16* __restrict__ h, const float* __restrict__ as,
                     const float* __restrict__ ad, float* __restrict__ al_s,
                     float* __restrict__ al_d, int N, int H, int F) {
  int wave = (blockIdx.x * blockDim.x + threadIdx.x) >> 6;
  int lane = threadIdx.x & 63;
  if (wave >= N) return;
  const bf16* hrow = h + (size_t)wave * H * F;
  for (int hd = 0; hd < H; ++hd) {
    float ss = 0.f, sd = 0.f;
    for (int f = lane; f < F; f += 64) {
      float v = __bfloat162float(hrow[hd * F + f]);
      ss += v * as[hd * F + f];
      sd += v * ad[hd * F + f];
    }
#pragma unroll
    for (int off = 32; off; off >>= 1) {
      ss += __shfl_xor(ss, off, 64);
      sd += __shfl_xor(sd, off, 64);
    }
    if (lane == 0) { al_s[wave * H + hd] = ss; al_d[wave * H + hd] = sd; }
  }
}

// -------- fused segment-softmax + weighted aggregation: one wave per node --------
// Pass 1: lane-parallel max over incoming edges.
// Pass 2 (per 64-edge chunk): lane e computes exp for edge e ONCE (lane-parallel),
// den via one wave-reduce; serial 8-deep accumulation loop broadcasts src & alpha
// from lane r via __shfl (uniform index -> readlane, overlaps VALU). Invalid tail
// lanes carry mys=0/alpha=0 -> dummy gather of row 0 (L1-hot), contribution 0.

template <int H, typename OT>
__global__ void k_attn_agg(const bf16* __restrict__ hbuf, const int* __restrict__ ssrc,
                           const int* __restrict__ offs, const float* __restrict__ al_s,
                           const float* __restrict__ al_d, const float* __restrict__ bias,
                           OT* __restrict__ out, int N) {
  int n = (blockIdx.x * blockDim.x + threadIdx.x) >> 6;
  int lane = threadIdx.x & 63;
  if (n >= N) return;
  int start = offs[n], end = offs[n + 1];
  float ald[H], mx[H];
#pragma unroll
  for (int hd = 0; hd < H; ++hd) { ald[hd] = al_d[n * H + hd]; mx[hd] = -1e30f; }

  // pass 1: lane-parallel max
  for (int pos = start + lane; pos < end; pos += 64) {
    int s = ssrc[pos];
#pragma unroll
    for (int hd = 0; hd < H; ++hd)
      mx[hd] = fmaxf(mx[hd], lrelu(al_s[s * H + hd] + ald[hd]));
  }
#pragma unroll
  for (int hd = 0; hd < H; ++hd)
#pragma unroll
    for (int off = 32; off; off >>= 1) mx[hd] = fmaxf(mx[hd], __shfl_xor(mx[hd], off, 64));

  int f0 = lane * 2;
  float den[H], accx[H], accy[H];
#pragma unroll
  for (int hd = 0; hd < H; ++hd) { den[hd] = 0.f; accx[hd] = 0.f; accy[hd] = 0.f; }

  for (int cb = start; cb < end; cb += 64) {
    int cl = end - cb; if (cl > 64) cl = 64;
    // lane-parallel alpha for this chunk (one exp per edge per head, total)
    int mys = (lane < cl) ? ssrc[cb + lane] : 0;
    float myex[H];
#pragma unroll
    for (int hd = 0; hd < H; ++hd) {
      float e = lrelu(al_s[mys * H + hd] + ald[hd]);
      float ex = __expf(e - mx[hd]);
      myex[hd] = (lane < cl) ? ex : 0.f;
    }
    // den via wave reduce
#pragma unroll
    for (int hd = 0; hd < H; ++hd) {
      float d = myex[hd];
#pragma unroll
      for (int off = 32; off; off >>= 1) d += __shfl_xor(d, off, 64);
      den[hd] += d;
    }
    // serial accumulation, 8-deep unroll, src/alpha via broadcast
    for (int r = 0; r < cl; r += 8) {
      int su[8];
      float a[8][H];
#pragma unroll
      for (int u = 0; u < 8; ++u) {
        su[u] = __shfl(mys, r + u, 64);
#pragma unroll
        for (int hd = 0; hd < H; ++hd) a[u][hd] = __shfl(myex[hd], r + u, 64);
      }
      bf16x2 v[8][H];
#pragma unroll
      for (int u = 0; u < 8; ++u) {
        const bf16* hp = hbuf + (size_t)su[u] * (H * 128) + f0;
#pragma unroll
        for (int hd = 0; hd < H; ++hd) v[u][hd] = *(const bf16x2*)(hp + hd * 128);
      }
#pragma unroll
      for (int u = 0; u < 8; ++u)
#pragma unroll
        for (int hd = 0; hd < H; ++hd) {
          float2 f = __bfloat1622float2(v[u][hd]);
          accx[hd] += a[u][hd] * f.x;
          accy[hd] += a[u][hd] * f.y;
        }
    }
  }
#pragma unroll
  for (int hd = 0; hd < H; ++hd) {
    float r = 1.f / (den[hd] + 1e-16f);
    float ox = lrelu(accx[hd] * r + bias[hd * 128 + f0]);
    float oy = lrelu(accy[hd] * r + bias[hd * 128 + f0 + 1]);
    st2_nt(&out[((size_t)n * H + hd) * 128 + f0], ox, oy);
  }
}

// ---------------- global mean pool: one wave per graph, no atomics ----------------

__global__ void k_pool(const float* __restrict__ h, const int* __restrict__ goffs,
                       float* __restrict__ out, int G) {
  int g = (blockIdx.x * blockDim.x + threadIdx.x) >> 6;
  int lane = threadIdx.x & 63;
  if (g >= G) return;
  int s = goffs[g], e = goffs[g + 1];
  float ax = 0.f, ay = 0.f;
  for (int n = s; n < e; ++n) {
    float2 v = *(const float2*)&h[(size_t)n * 128 + lane * 2];
    ax += v.x; ay += v.y;
  }
  float c = fmaxf((float)(e - s), 1.f);
  st2(&out[(size_t)g * 128 + lane * 2], ax / c, ay / c);
}

// ---------------- host launcher ----------------

extern "C" void kernel_launch(void* const* d_in, const int* in_sizes, int n_in,
                              void* d_out, int out_size, void* d_ws, size_t ws_size,
                              hipStream_t stream) {
  const float* x   = (const float*)d_in[0];
  const int*   ei  = (const int*)d_in[1];
  const int*   bat = (const int*)d_in[2];
  const float* W1  = (const float*)d_in[3];
  const float* a1s = (const float*)d_in[4];
  const float* a1d = (const float*)d_in[5];
  const float* b1  = (const float*)d_in[6];
  const float* W2  = (const float*)d_in[7];
  const float* a2s = (const float*)d_in[8];
  const float* a2d = (const float*)d_in[9];
  const float* b2  = (const float*)d_in[10];
  const float* W3  = (const float*)d_in[11];
  const float* a3s = (const float*)d_in[12];
  const float* a3d = (const float*)d_in[13];
  const float* b3  = (const float*)d_in[14];
  float* out = (float*)d_out;

  const int N = in_sizes[2];          // 200000
  const int E = in_sizes[1] / 2;      // 1600000
  const int Et = E + N;               // with self-loops
  const int G = out_size / 128;       // 5000
  const int H = 3;

  // ---- workspace carve (bf16 intermediates) ----
  char* p = (char*)d_ws;
  auto carve = [&](size_t bytes) { void* r = (void*)p; p += (bytes + 255) & ~(size_t)255; return r; };
  bf16*  bufA   = (bf16*)carve((size_t)N * 384 * 2);   // agg out / GEMM A; also hosts xb & fp32 layer-3 out
  bf16*  bufB   = (bf16*)carve((size_t)N * 384 * 2);   // GEMM output h
  float* al_s   = (float*)carve((size_t)N * 3 * 4);
  float* al_d   = (float*)carve((size_t)N * 3 * 4);
  int*   ssrc   = (int*)carve((size_t)Et * 4);
  int*   offs   = (int*)carve((size_t)(N + 1) * 4);
  int*   deg    = (int*)carve((size_t)N * 4);
  int*   cur    = (int*)carve((size_t)N * 4);
  int*   bsum   = (int*)carve(4096 * 4);
  int*   gdeg   = (int*)carve((size_t)G * 4);
  int*   goffs  = (int*)carve((size_t)(G + 1) * 4);
  bf16*  Wt1    = (bf16*)carve((size_t)384 * 128 * 2);
  bf16*  Wt2    = (bf16*)carve((size_t)384 * 384 * 2);
  bf16*  Wt3    = (bf16*)carve((size_t)128 * 384 * 2);
  size_t need = (size_t)(p - (char*)d_ws);

  if (ws_size < need) {
    k_zero_out<<<(out_size + 255) / 256, 256, 0, stream>>>(out, out_size);
    return;
  }

  const int* esrc = ei;
  const int* edst = ei + E;

  int ebl = (Et + 255) / 256;
  int NB = (N + 1023) / 1024;
  int GB = (G + 1023) / 1024;
  int nodeWaveBlocks = (N * 64 + 255) / 256;

  // ---- prep: weight transpose+cast, x cast (xb aliases bufA) ----
  bf16* xb = bufA;
  k_cvt<<<((long)N * 128 + 255) / 256, 256, 0, stream>>>(x, xb, (long)N * 128);
  k_tw<<<(128 * 384 + 255) / 256, 256, 0, stream>>>(W1, Wt1, 128, 384);
  k_tw<<<(384 * 384 + 255) / 256, 256, 0, stream>>>(W2, Wt2, 384, 384);
  k_tw<<<(384 * 128 + 255) / 256, 256, 0, stream>>>(W3, Wt3, 384, 128);

  // ---- sort edges by dst ----
  k_zero<<<(N + 255) / 256, 256, 0, stream>>>((unsigned int*)deg, N);
  k_hist<<<ebl, 256, 0, stream>>>(edst, deg, E, Et);
  k_scan1<<<NB, 256, 0, stream>>>(deg, offs, bsum, N);
  k_scan2<<<1, 64, 0, stream>>>(bsum, NB);
  k_scan3<<<NB, 256, 0, stream>>>(offs, bsum, N, Et);
  k_zero<<<(N + 255) / 256, 256, 0, stream>>>((unsigned int*)cur, N);
  k_scatter<<<ebl, 256, 0, stream>>>(esrc, edst, offs, cur, ssrc, E, Et);

  // ---- graph offsets for pool (batch is sorted) ----
  k_zero<<<(G + 255) / 256, 256, 0, stream>>>((unsigned int*)gdeg, G);
  k_hist1<<<(N + 255) / 256, 256, 0, stream>>>(bat, gdeg, N);
  k_scan1<<<GB, 256, 0, stream>>>(gdeg, goffs, bsum, G);
  k_scan2<<<1, 64, 0, stream>>>(bsum, GB);
  k_scan3<<<GB, 256, 0, stream>>>(goffs, bsum, G, N);

  dim3 g1(N / 64, 6), g2(N / 64, 6), g3(N / 64, 2);

  // ---- layer 1: xb[N,128] @ W1 -> bufB[N,384] ----
  k_gemm_mfma<<<g1, 256, 0, stream>>>(xb, Wt1, bufB, 128, 384);
  k_al<<<nodeWaveBlocks, 256, 0, stream>>>(bufB, a1s, a1d, al_s, al_d, N, H, 128);
  k_attn_agg<3, bf16><<<nodeWaveBlocks, 256, 0, stream>>>(bufB, ssrc, offs, al_s, al_d, b1, bufA, N);

  // ---- layer 2: bufA[N,384] @ W2 -> bufB[N,384] ----
  k_gemm_mfma<<<g2, 256, 0, stream>>>(bufA, Wt2, bufB, 384, 384);
  k_al<<<nodeWaveBlocks, 256, 0, stream>>>(bufB, a2s, a2d, al_s, al_d, N, H, 128);
  k_attn_agg<3, bf16><<<nodeWaveBlocks, 256, 0, stream>>>(bufB, ssrc, offs, al_s, al_d, b2, bufA, N);

  // ---- layer 3: bufA[N,384] @ W3 -> bufB[N,128], heads=1, fp32 agg out ----
  k_gemm_mfma<<<g3, 256, 0, stream>>>(bufA, Wt3, bufB, 384, 128);
  k_al<<<nodeWaveBlocks, 256, 0, stream>>>(bufB, a3s, a3d, al_s, al_d, N, 1, 128);
  float* out3 = (float*)bufA;
  k_attn_agg<1, float><<<nodeWaveBlocks, 256, 0, stream>>>(bufB, ssrc, offs, al_s, al_d, b3, out3, N);

  // ---- global mean pool: segmented, atomic-free ----
  k_pool<<<(G * 64 + 255) / 256, 256, 0, stream>>>(out3, goffs, out, G);
}

// Round 8
// 1469.364 us; speedup vs baseline: 1.1305x; 1.1305x over previous
//
#include <hip/hip_runtime.h>
#include <hip/hip_bf16.h>
#include <math.h>

#define LRELU_SLOPE 0.2f
typedef __hip_bfloat16 bf16;
typedef __hip_bfloat162 bf16x2;

typedef short s8v __attribute__((ext_vector_type(8)));   // 8 bf16 (4 VGPRs)
typedef float f4v __attribute__((ext_vector_type(4)));   // MFMA acc

__device__ __forceinline__ float lrelu(float v) { return v > 0.f ? v : LRELU_SLOPE * v; }
__device__ __forceinline__ float b2f(short b) {
  return __uint_as_float(((unsigned)(unsigned short)b) << 16);
}

__device__ __forceinline__ void st2(bf16* p, float x, float y) {
  float2 f{x, y};
  *(bf16x2*)p = __float22bfloat162_rn(f);
}
__device__ __forceinline__ void st2(float* p, float x, float y) {
  *(float2*)p = float2{x, y};
}

// nontemporal variants: streaming output shouldn't evict the h gather set
__device__ __forceinline__ void st2_nt(bf16* p, float x, float y) {
  float2 f{x, y};
  bf16x2 v = __float22bfloat162_rn(f);
  __builtin_nontemporal_store(*(unsigned int*)&v, (unsigned int*)p);
}
__device__ __forceinline__ void st2_nt(float* p, float x, float y) {
  __builtin_nontemporal_store(x, p);
  __builtin_nontemporal_store(y, p + 1);
}

// ---------------- zero helper (avoid hipMemsetAsync in capture) ----------------

__global__ void k_zero(unsigned int* __restrict__ p, long n) {
  long i = (long)blockIdx.x * blockDim.x + threadIdx.x;
  if (i < n) p[i] = 0u;
}

__global__ void k_zero_out(float* __restrict__ out, int n) {
  int i = blockIdx.x * blockDim.x + threadIdx.x;
  if (i < n) out[i] = 0.f;
}

// ---------------- dtype prep: x -> bf16, W -> bf16 transposed ----------------

__global__ void k_cvt(const float* __restrict__ x, bf16* __restrict__ xb, long n) {
  long i = (long)blockIdx.x * blockDim.x + threadIdx.x;
  if (i < n) xb[i] = __float2bfloat16(x[i]);
}

// W[K][NN] (f32) -> Wt[NN][K] (bf16)
__global__ void k_tw(const float* __restrict__ W, bf16* __restrict__ Wt, int K, int NN) {
  int i = blockIdx.x * blockDim.x + threadIdx.x;
  if (i >= K * NN) return;
  int k = i / NN, n = i - k * NN;
  Wt[(size_t)n * K + k] = __float2bfloat16(W[i]);
}

// ---------------- preprocessing: counting-sort edges by dst ----------------

__global__ void k_hist(const int* __restrict__ dst, int* __restrict__ deg, int E, int Et) {
  int e = blockIdx.x * blockDim.x + threadIdx.x;
  if (e >= Et) return;
  int d = (e < E) ? dst[e] : (e - E);   // self-loops appended
  atomicAdd(&deg[d], 1);
}

__global__ void k_hist1(const int* __restrict__ idx, int* __restrict__ deg, int n) {
  int i = blockIdx.x * blockDim.x + threadIdx.x;
  if (i < n) atomicAdd(&deg[idx[i]], 1);
}

__global__ void k_scan1(const int* __restrict__ deg, int* __restrict__ offs,
                        int* __restrict__ bsum, int n) {
  __shared__ int sd[256];
  int t = threadIdx.x;
  int base = blockIdx.x * 1024 + t * 4;
  int v[4]; int tsum = 0;
#pragma unroll
  for (int i = 0; i < 4; ++i) { v[i] = (base + i < n) ? deg[base + i] : 0; tsum += v[i]; }
  sd[t] = tsum;
  __syncthreads();
  for (int off = 1; off < 256; off <<= 1) {
    int x = (t >= off) ? sd[t - off] : 0;
    __syncthreads();
    sd[t] += x;
    __syncthreads();
  }
  int excl = sd[t] - tsum;
#pragma unroll
  for (int i = 0; i < 4; ++i) { if (base + i < n) offs[base + i] = excl; excl += v[i]; }
  if (t == 255) bsum[blockIdx.x] = sd[255];
}

__global__ void k_scan2(int* bsum, int nb) {
  if (threadIdx.x == 0 && blockIdx.x == 0) {
    int run = 0;
    for (int i = 0; i < nb; ++i) { int t = bsum[i]; bsum[i] = run; run += t; }
  }
}

__global__ void k_scan3(int* __restrict__ offs, const int* __restrict__ bsum, int n, int total) {
  int t = threadIdx.x;
  int base = blockIdx.x * 1024 + t * 4;
  int add = bsum[blockIdx.x];
#pragma unroll
  for (int i = 0; i < 4; ++i) if (base + i < n) offs[base + i] += add;
  if (blockIdx.x == 0 && t == 0) offs[n] = total;
}

__global__ void k_scatter(const int* __restrict__ src, const int* __restrict__ dst,
                          const int* __restrict__ offs, int* __restrict__ cur,
                          int* __restrict__ ssrc, int E, int Et) {
  int e = blockIdx.x * blockDim.x + threadIdx.x;
  if (e >= Et) return;
  int s, d;
  if (e < E) { s = src[e]; d = dst[e]; } else { s = d = e - E; }
  int pos = offs[d] + atomicAdd(&cur[d], 1);
  ssrc[pos] = s;
}

// ---------------- bf16 MFMA GEMM: C[M,NN](bf16) = A[M,K](bf16) @ Wt[NN,K](bf16)^T ----

__global__ __launch_bounds__(256) void k_gemm_mfma(const bf16* __restrict__ A,
                                                   const bf16* __restrict__ Wt,
                                                   bf16* __restrict__ C,
                                                   int K, int NN) {
  __shared__ __align__(16) short sA[64 * 64];   // 8 KB, 64 rows x 64 cols bf16
  int t = threadIdx.x;
  int wv = t >> 6, lane = t & 63;
  int quad = lane >> 4, l15 = lane & 15;
  size_t bm0 = (size_t)blockIdx.x * 64;
  int bn0 = blockIdx.y * 64;
  const bf16* Ab = A + bm0 * K;
  const bf16* Bp = Wt + (size_t)(bn0 + wv * 16 + l15) * K;  // this lane's weight row
  f4v acc[4] = {f4v{0,0,0,0}, f4v{0,0,0,0}, f4v{0,0,0,0}, f4v{0,0,0,0}};

  for (int kb = 0; kb < K; kb += 64) {
#pragma unroll
    for (int j = 0; j < 2; ++j) {
      int idx = j * 256 + t;
      int row = idx >> 3, p = idx & 7;
      int c = p ^ (row & 7);                  // global 16B-chunk landing at pos p
      const bf16* g = Ab + (size_t)row * K + kb + c * 8;
      __builtin_amdgcn_global_load_lds(
          (const __attribute__((address_space(1))) void*)g,
          (__attribute__((address_space(3))) void*)((char*)sA + (size_t)(j * 256 + wv * 64) * 16),
          16, 0, 0);
    }
    __syncthreads();
#pragma unroll
    for (int kk = 0; kk < 2; ++kk) {
      s8v bfrag = *(const s8v*)(Bp + kb + kk * 32 + quad * 8);
#pragma unroll
      for (int ms = 0; ms < 4; ++ms) {
        int row = ms * 16 + l15;
        int pos = (kk * 4 + quad) ^ (row & 7);
        s8v afrag = *(const s8v*)((const char*)sA + (size_t)row * 128 + pos * 16);
        acc[ms] = __builtin_amdgcn_mfma_f32_16x16x32_bf16(afrag, bfrag, acc[ms], 0, 0, 0);
      }
    }
    __syncthreads();
  }
  // C/D layout: col = lane&15, row = quad*4 + reg  [m89/m91 verified]
  int coln = bn0 + wv * 16 + l15;
#pragma unroll
  for (int ms = 0; ms < 4; ++ms)
#pragma unroll
    for (int r = 0; r < 4; ++r)
      C[(bm0 + ms * 16 + quad * 4 + r) * NN + coln] = __float2bfloat16(acc[ms][r]);
}

// ---------------- attention logits: one wave per node, 16 lanes per head ----------------
// Lane (hd*16 + g) loads 8 bf16 (16B) of head hd; idle lane groups alias head 0's
// addresses (wave-coalesced, no extra traffic) and never write.

template <int H>
__global__ void k_al(const bf16* __restrict__ h, const float* __restrict__ as,
                     const float* __restrict__ ad, float* __restrict__ al_s,
                     float* __restrict__ al_d, int N) {
  int n = (blockIdx.x * blockDim.x + threadIdx.x) >> 6;
  int lane = threadIdx.x & 63;
  if (n >= N) return;
  int hd = lane >> 4;
  bool active = (hd < H);
  int hdc = active ? hd : 0;
  int f8 = (lane & 15) * 8;
  const bf16* hp = h + (size_t)n * (H * 128) + hdc * 128 + f8;
  s8v hv = *(const s8v*)hp;
  float ss = 0.f, sd = 0.f;
#pragma unroll
  for (int i = 0; i < 8; ++i) {
    float v = b2f(hv[i]);
    ss += v * as[hdc * 128 + f8 + i];
    sd += v * ad[hdc * 128 + f8 + i];
  }
#pragma unroll
  for (int off = 8; off; off >>= 1) {
    ss += __shfl_xor(ss, off, 64);
    sd += __shfl_xor(sd, off, 64);
  }
  if (active && (lane & 15) == 0) {
    al_s[n * H + hd] = ss;
    al_d[n * H + hd] = sd;
  }
}

// -------- fused segment-softmax + weighted aggregation: one wave per node --------
// Pass 1: lane-parallel max. Pass 2 per 64-edge chunk: lane e computes exp once
// (lane-parallel), stashes {src, ex[H]} in LDS; serial 8-deep loop reads edge
// records via same-address ds_read (broadcast, conflict-free) while up to 24
// gathers are in flight. den accumulates from broadcast values (wave-uniform).

template <int H, typename OT>
__global__ __launch_bounds__(256) void k_attn_agg(const bf16* __restrict__ hbuf,
                           const int* __restrict__ ssrc,
                           const int* __restrict__ offs, const float* __restrict__ al_s,
                           const float* __restrict__ al_d, const float* __restrict__ bias,
                           OT* __restrict__ out, int N) {
  constexpr int SW = (H > 1) ? 4 : 2;
  __shared__ __align__(16) float stash[4][64 * SW];
  int n = (blockIdx.x * blockDim.x + threadIdx.x) >> 6;
  int lane = threadIdx.x & 63;
  if (n >= N) return;
  float* st = stash[threadIdx.x >> 6];
  int start = offs[n], end = offs[n + 1];
  float ald[H], mx[H];
#pragma unroll
  for (int hd = 0; hd < H; ++hd) { ald[hd] = al_d[n * H + hd]; mx[hd] = -1e30f; }

  // pass 1: lane-parallel max
  for (int pos = start + lane; pos < end; pos += 64) {
    int s = ssrc[pos];
#pragma unroll
    for (int hd = 0; hd < H; ++hd)
      mx[hd] = fmaxf(mx[hd], lrelu(al_s[s * H + hd] + ald[hd]));
  }
#pragma unroll
  for (int hd = 0; hd < H; ++hd)
#pragma unroll
    for (int off = 32; off; off >>= 1) mx[hd] = fmaxf(mx[hd], __shfl_xor(mx[hd], off, 64));

  int f0 = lane * 2;
  float den[H], accx[H], accy[H];
#pragma unroll
  for (int hd = 0; hd < H; ++hd) { den[hd] = 0.f; accx[hd] = 0.f; accy[hd] = 0.f; }

  for (int cb = start; cb < end; cb += 64) {
    int cl = end - cb; if (cl > 64) cl = 64;
    // lane-parallel alpha (one exp per edge per head total)
    int mys = (lane < cl) ? ssrc[cb + lane] : 0;
    float myex[H];
#pragma unroll
    for (int hd = 0; hd < H; ++hd) {
      float e = lrelu(al_s[mys * H + hd] + ald[hd]);
      float ex = __expf(e - mx[hd]);
      myex[hd] = (lane < cl) ? ex : 0.f;
    }
    // stash this chunk's edge records (wave-private region; wave-synchronous)
    __builtin_amdgcn_wave_barrier();
    if (H > 1) {
      float4 s4{__int_as_float(mys), myex[0], myex[1], myex[2]};
      *(float4*)&st[lane * 4] = s4;
    } else {
      float2 s2{__int_as_float(mys), myex[0]};
      *(float2*)&st[lane * 2] = s2;
    }
    asm volatile("s_waitcnt lgkmcnt(0)" ::: "memory");
    __builtin_amdgcn_wave_barrier();

    for (int r = 0; r < cl; r += 8) {
      int su[8];
      float a[8][H];
#pragma unroll
      for (int u = 0; u < 8; ++u) {
        if (H > 1) {
          float4 ed = *(const float4*)&st[(r + u) * 4];
          su[u] = __float_as_int(ed.x);
          a[u][0] = ed.y;
          if (H > 1) { a[u][1] = ed.z; a[u][2] = ed.w; }
        } else {
          float2 ed = *(const float2*)&st[(r + u) * 2];
          su[u] = __float_as_int(ed.x);
          a[u][0] = ed.y;
        }
      }
      bf16x2 v[8][H];
#pragma unroll
      for (int u = 0; u < 8; ++u) {
        const bf16* hp = hbuf + (size_t)su[u] * (H * 128) + f0;
#pragma unroll
        for (int hd = 0; hd < H; ++hd) v[u][hd] = *(const bf16x2*)(hp + hd * 128);
      }
#pragma unroll
      for (int u = 0; u < 8; ++u)
#pragma unroll
        for (int hd = 0; hd < H; ++hd) {
          float2 f = __bfloat1622float2(v[u][hd]);
          accx[hd] += a[u][hd] * f.x;
          accy[hd] += a[u][hd] * f.y;
          if (hd == 0) {}  // keep structure simple
        }
      // den from broadcast values (identical across lanes; tail entries are 0)
#pragma unroll
      for (int u = 0; u < 8; ++u)
#pragma unroll
        for (int hd = 0; hd < H; ++hd) den[hd] += a[u][hd];
    }
  }
#pragma unroll
  for (int hd = 0; hd < H; ++hd) {
    float r = 1.f / (den[hd] + 1e-16f);
    float ox = lrelu(accx[hd] * r + bias[hd * 128 + f0]);
    float oy = lrelu(accy[hd] * r + bias[hd * 128 + f0 + 1]);
    st2_nt(&out[((size_t)n * H + hd) * 128 + f0], ox, oy);
  }
}

// ---------------- global mean pool: one wave per graph, no atomics ----------------

__global__ void k_pool(const float* __restrict__ h, const int* __restrict__ goffs,
                       float* __restrict__ out, int G) {
  int g = (blockIdx.x * blockDim.x + threadIdx.x) >> 6;
  int lane = threadIdx.x & 63;
  if (g >= G) return;
  int s = goffs[g], e = goffs[g + 1];
  float ax = 0.f, ay = 0.f;
  for (int n = s; n < e; ++n) {
    float2 v = *(const float2*)&h[(size_t)n * 128 + lane * 2];
    ax += v.x; ay += v.y;
  }
  float c = fmaxf((float)(e - s), 1.f);
  st2(&out[(size_t)g * 128 + lane * 2], ax / c, ay / c);
}

// ---------------- host launcher ----------------

extern "C" void kernel_launch(void* const* d_in, const int* in_sizes, int n_in,
                              void* d_out, int out_size, void* d_ws, size_t ws_size,
                              hipStream_t stream) {
  const float* x   = (const float*)d_in[0];
  const int*   ei  = (const int*)d_in[1];
  const int*   bat = (const int*)d_in[2];
  const float* W1  = (const float*)d_in[3];
  const float* a1s = (const float*)d_in[4];
  const float* a1d = (const float*)d_in[5];
  const float* b1  = (const float*)d_in[6];
  const float* W2  = (const float*)d_in[7];
  const float* a2s = (const float*)d_in[8];
  const float* a2d = (const float*)d_in[9];
  const float* b2  = (const float*)d_in[10];
  const float* W3  = (const float*)d_in[11];
  const float* a3s = (const float*)d_in[12];
  const float* a3d = (const float*)d_in[13];
  const float* b3  = (const float*)d_in[14];
  float* out = (float*)d_out;

  const int N = in_sizes[2];          // 200000
  const int E = in_sizes[1] / 2;      // 1600000
  const int Et = E + N;               // with self-loops
  const int G = out_size / 128;       // 5000

  // ---- workspace carve (bf16 intermediates) ----
  char* p = (char*)d_ws;
  auto carve = [&](size_t bytes) { void* r = (void*)p; p += (bytes + 255) & ~(size_t)255; return r; };
  bf16*  bufA   = (bf16*)carve((size_t)N * 384 * 2);   // agg out / GEMM A; also hosts xb & fp32 layer-3 out
  bf16*  bufB   = (bf16*)carve((size_t)N * 384 * 2);   // GEMM output h
  float* al_s   = (float*)carve((size_t)N * 3 * 4);
  float* al_d   = (float*)carve((size_t)N * 3 * 4);
  int*   ssrc   = (int*)carve((size_t)Et * 4);
  int*   offs   = (int*)carve((size_t)(N + 1) * 4);
  int*   deg    = (int*)carve((size_t)N * 4);
  int*   cur    = (int*)carve((size_t)N * 4);
  int*   bsum   = (int*)carve(4096 * 4);
  int*   gdeg   = (int*)carve((size_t)G * 4);
  int*   goffs  = (int*)carve((size_t)(G + 1) * 4);
  bf16*  Wt1    = (bf16*)carve((size_t)384 * 128 * 2);
  bf16*  Wt2    = (bf16*)carve((size_t)384 * 384 * 2);
  bf16*  Wt3    = (bf16*)carve((size_t)128 * 384 * 2);
  size_t need = (size_t)(p - (char*)d_ws);

  if (ws_size < need) {
    k_zero_out<<<(out_size + 255) / 256, 256, 0, stream>>>(out, out_size);
    return;
  }

  const int* esrc = ei;
  const int* edst = ei + E;

  int ebl = (Et + 255) / 256;
  int NB = (N + 1023) / 1024;
  int GB = (G + 1023) / 1024;
  int nodeWaveBlocks = (N * 64 + 255) / 256;

  // ---- prep: weight transpose+cast, x cast (xb aliases bufA) ----
  bf16* xb = bufA;
  k_cvt<<<((long)N * 128 + 255) / 256, 256, 0, stream>>>(x, xb, (long)N * 128);
  k_tw<<<(128 * 384 + 255) / 256, 256, 0, stream>>>(W1, Wt1, 128, 384);
  k_tw<<<(384 * 384 + 255) / 256, 256, 0, stream>>>(W2, Wt2, 384, 384);
  k_tw<<<(384 * 128 + 255) / 256, 256, 0, stream>>>(W3, Wt3, 384, 128);

  // ---- sort edges by dst ----
  k_zero<<<(N + 255) / 256, 256, 0, stream>>>((unsigned int*)deg, N);
  k_hist<<<ebl, 256, 0, stream>>>(edst, deg, E, Et);
  k_scan1<<<NB, 256, 0, stream>>>(deg, offs, bsum, N);
  k_scan2<<<1, 64, 0, stream>>>(bsum, NB);
  k_scan3<<<NB, 256, 0, stream>>>(offs, bsum, N, Et);
  k_zero<<<(N + 255) / 256, 256, 0, stream>>>((unsigned int*)cur, N);
  k_scatter<<<ebl, 256, 0, stream>>>(esrc, edst, offs, cur, ssrc, E, Et);

  // ---- graph offsets for pool (batch is sorted) ----
  k_zero<<<(G + 255) / 256, 256, 0, stream>>>((unsigned int*)gdeg, G);
  k_hist1<<<(N + 255) / 256, 256, 0, stream>>>(bat, gdeg, N);
  k_scan1<<<GB, 256, 0, stream>>>(gdeg, goffs, bsum, G);
  k_scan2<<<1, 64, 0, stream>>>(bsum, GB);
  k_scan3<<<GB, 256, 0, stream>>>(goffs, bsum, G, N);

  dim3 g1(N / 64, 6), g2(N / 64, 6), g3(N / 64, 2);

  // ---- layer 1: xb[N,128] @ W1 -> bufB[N,384] ----
  k_gemm_mfma<<<g1, 256, 0, stream>>>(xb, Wt1, bufB, 128, 384);
  k_al<3><<<nodeWaveBlocks, 256, 0, stream>>>(bufB, a1s, a1d, al_s, al_d, N);
  k_attn_agg<3, bf16><<<nodeWaveBlocks, 256, 0, stream>>>(bufB, ssrc, offs, al_s, al_d, b1, bufA, N);

  // ---- layer 2: bufA[N,384] @ W2 -> bufB[N,384] ----
  k_gemm_mfma<<<g2, 256, 0, stream>>>(bufA, Wt2, bufB, 384, 384);
  k_al<3><<<nodeWaveBlocks, 256, 0, stream>>>(bufB, a2s, a2d, al_s, al_d, N);
  k_attn_agg<3, bf16><<<nodeWaveBlocks, 256, 0, stream>>>(bufB, ssrc, offs, al_s, al_d, b2, bufA, N);

  // ---- layer 3: bufA[N,384] @ W3 -> bufB[N,128], heads=1, fp32 agg out ----
  k_gemm_mfma<<<g3, 256, 0, stream>>>(bufA, Wt3, bufB, 384, 128);
  k_al<1><<<nodeWaveBlocks, 256, 0, stream>>>(bufB, a3s, a3d, al_s, al_d, N);
  float* out3 = (float*)bufA;
  k_attn_agg<1, float><<<nodeWaveBlocks, 256, 0, stream>>>(bufB, ssrc, offs, al_s, al_d, b3, out3, N);

  // ---- global mean pool: segmented, atomic-free ----
  k_pool<<<(G * 64 + 255) / 256, 256, 0, stream>>>(out3, goffs, out, G);
}